// Round 11
// baseline (224.019 us; speedup 1.0000x reference)
//
#include <hip/hip_runtime.h>
#include <hip/hip_fp16.h>

// DPMultiHeadAttention MI355X — Round 20.
// R19 confirmed: fp16 single-pass = 209.7us total (was 243.8), absmax 1.95e-3,
// attention stable 84.6us. Non-attention ~125us vs ~55us floor -> GEMM slack.
// R20, two separable changes:
// (1) gemm_qkv launch_bounds (256,3)->(256,4): post-R18 hard-live set is
//     acc 64 + frags 32 + addr ~20 ≈ 116 regs < 128 cap (R15's spill was cap
//     85 vs >90 hard-live — different regime). LDS 32KB fits 4 blocks/CU.
//     16 waves/CU (from 12) hides staging. Failure signature: gemm_qkv in
//     top-5 with huge WRITE_SIZE -> revert.
// (2) gemm_out 128x128 tile (grid (32,8)), cloning the proven gemm_qkv
//     K-loop; staging B/elem 48->32, A-redundancy halves. Kept at (256,3)
//     to isolate (1). Per-element math order unchanged -> absmax identical.

constexpr int B  = 2;
constexpr int S  = 2048;
constexpr int D  = 1024;
constexpr int H  = 16;
constexpr int DH = 64;
constexpr int BS = B * S;   // 4096

using u16 = unsigned short;
using u32 = unsigned int;
using frag8h = __attribute__((ext_vector_type(8)))  _Float16;
using f32x4  = __attribute__((ext_vector_type(4)))  float;
using f32x16 = __attribute__((ext_vector_type(16))) float;

__device__ inline u16 f2h(float x) {
    __half t = __float2half_rn(x);
    union { __half h; u16 u; } c; c.h = t; return c.u;
}
__device__ inline u32 pk2h(float a, float b) {
    __half2 t = __float22half2_rn(make_float2(a, b));
    union { __half2 h; u32 u; } c; c.h = t; return c.u;
}

#if __has_builtin(__builtin_amdgcn_exp2f)
#define EXP2(x) __builtin_amdgcn_exp2f(x)
#else
#define EXP2(x) exp2f(x)
#endif

__device__ inline void glds16(const u16* g, const u16* l) {
    __builtin_amdgcn_global_load_lds(
        (const __attribute__((address_space(1))) void*)g,
        (__attribute__((address_space(3))) void*)l, 16, 0, 0);
}

// score scale: 1/sqrt(DH) * log2(e) (exp2-domain softmax), folded into K
#define KSC (0.125f * 1.44269504088896f)

// ---------------------------------------------------------------------------
// convert_x: x fp32 [4096][1024] -> xh fp16 (single array; no split)
// ---------------------------------------------------------------------------
__global__ __launch_bounds__(256) void convert_x(
    const float* __restrict__ x, u16* __restrict__ xh)
{
    const size_t idx = ((size_t)blockIdx.x * 256 + threadIdx.x) * 4;
    float4 v = *(const float4*)&x[idx];
    *(uint2*)&xh[idx] = make_uint2(pk2h(v.x, v.y), pk2h(v.z, v.w));
}

// ---------------------------------------------------------------------------
// transpose_w: Wt[4096][1024] fp16, k-contiguous rows.
// rows [0,3072): Wt[(t*16+h)*64+e][k] = W_t[h][k][e]; rows [3072,4096): Wo^T.
// ---------------------------------------------------------------------------
__global__ __launch_bounds__(256) void transpose_w(
    const float* __restrict__ Wq, const float* __restrict__ Wk,
    const float* __restrict__ Wv, const float* __restrict__ Wo,
    u16* __restrict__ Wt)
{
    const int kt = blockIdx.x;      // 0..15
    const int sl = blockIdx.y;      // 0..63
    const int tid = threadIdx.x;
    __shared__ float Ls[64][68];

    const float* src; int rstride;
    if (sl < 48) {
        const int t = sl >> 4, h = sl & 15;
        const float* Wp = (t == 0) ? Wq : ((t == 1) ? Wk : Wv);
        src = Wp + (size_t)h * D * DH;
        rstride = 64;
    } else {
        src = Wo + (sl - 48) * 64;
        rstride = 1024;
    }

    const int rr = tid >> 4, c4 = tid & 15;
#pragma unroll
    for (int p = 0; p < 4; ++p) {
        const int kk = p * 16 + rr;
        float4 v = *(const float4*)&src[(size_t)(kt * 64 + kk) * rstride + c4 * 4];
        *(float4*)&Ls[kk][c4 * 4] = v;
    }
    __syncthreads();
    const int rl = tid >> 2, ks = tid & 3;
    u16 ob[16];
#pragma unroll
    for (int i = 0; i < 16; ++i) ob[i] = f2h(Ls[ks * 16 + i][rl]);
    u16* dst = Wt + (size_t)(sl * 64 + rl) * 1024 + kt * 64 + ks * 16;
    *(uint4*)&dst[0] = *(uint4*)&ob[0];
    *(uint4*)&dst[8] = *(uint4*)&ob[8];
}

// ---------------------------------------------------------------------------
// gemm_qkv: C[n][s] = sum_k Wt[n,k]*x[s,k]. fp16 single-pass.
// 128x128 tile, 32 MFMA per barrier pair. grid (32,24): x=s-tile, y=n-tile.
// launch_bounds(256,4): hard-live ~116 regs < 128 cap -> 4 blocks/CU.
// Epilogue: q -> qh row-major [bh][s][64]; k -> khF (scaled KSC); v -> vhF.
// Fragment granule per (bh,kt): off = ((sub*4+ks)*64+lane)*8+j
// ---------------------------------------------------------------------------
__global__ __launch_bounds__(256, 4) void gemm_qkv(
    const u16* __restrict__ Wt, const u16* __restrict__ xh,
    const float* __restrict__ bq, const float* __restrict__ bk, const float* __restrict__ bv,
    u16* __restrict__ qhO, u16* __restrict__ khF, u16* __restrict__ vhF)
{
    const int r0  = blockIdx.y * 128;     // n
    const int c0  = blockIdx.x * 128;     // s
    const int tid = threadIdx.x;
    const int w = tid >> 6, lane = tid & 63;
    const int wi = w >> 1, wj = w & 1;
    const int ml = lane & 15, kg = lane >> 4;

    __shared__ u16 Ta[2][128 * 32];
    __shared__ u16 Tb[2][128 * 32];

    const int srow = lane >> 2, sseg = lane & 3;
    const u16* Ag = Wt + (size_t)(r0 + w * 32 + srow) * 1024 + sseg * 8;
    const u16* Bg = xh + (size_t)(c0 + w * 32 + srow) * 1024 + sseg * 8;

    f32x4 acc[4][4];
#pragma unroll
    for (int i = 0; i < 4; ++i)
#pragma unroll
        for (int j = 0; j < 4; ++j)
#pragma unroll
            for (int r = 0; r < 4; ++r) acc[i][j][r] = 0.f;

    for (int k0 = 0; k0 < 1024; k0 += 64) {
        __syncthreads();
#pragma unroll
        for (int hb = 0; hb < 2; ++hb) {
            const int ko = k0 + hb * 32;
            glds16(Ag + ko,             &Ta[hb][(w * 32) * 32]);
            glds16(Ag + 16 * 1024 + ko, &Ta[hb][(w * 32 + 16) * 32]);
            glds16(Bg + ko,             &Tb[hb][(w * 32) * 32]);
            glds16(Bg + 16 * 1024 + ko, &Tb[hb][(w * 32 + 16) * 32]);
        }
        __syncthreads();

#pragma unroll
        for (int hb = 0; hb < 2; ++hb) {
            frag8h af[4], bf[4];
#pragma unroll
            for (int i = 0; i < 4; ++i)
                af[i] = *(const frag8h*)&Ta[hb][(wi * 64 + i * 16 + ml) * 32 + kg * 8];
#pragma unroll
            for (int j = 0; j < 4; ++j)
                bf[j] = *(const frag8h*)&Tb[hb][(wj * 64 + j * 16 + ml) * 32 + kg * 8];
#pragma unroll
            for (int i = 0; i < 4; ++i)
#pragma unroll
                for (int j = 0; j < 4; ++j)
                    acc[i][j] = __builtin_amdgcn_mfma_f32_16x16x32_f16(af[i], bf[j], acc[i][j], 0, 0, 0);
        }
    }

    // epilogue: C/D col = ml (s), rows = n
    const int t = r0 >> 10;                      // 0:q 1:k 2:v
    if (t == 0) {
#pragma unroll
        for (int i = 0; i < 4; ++i) {
            const int Rb = r0 + wi * 64 + i * 16 + kg * 4;
            const int h  = (Rb >> 6) & 15;
            const int e0 = Rb & 63;
            float bv4[4];
#pragma unroll
            for (int r = 0; r < 4; ++r) bv4[r] = bq[(Rb & 1023) + r];
#pragma unroll
            for (int j = 0; j < 4; ++j) {
                const int s  = c0 + wj * 64 + j * 16 + ml;
                const int bb = s >> 11, sl = s & (S - 1);
                float v[4];
#pragma unroll
                for (int r = 0; r < 4; ++r) v[r] = acc[i][j][r] + bv4[r];
                const size_t base = ((size_t)(bb * H + h) * S + sl) * 64 + e0;
                *(uint2*)&qhO[base] = make_uint2(pk2h(v[0], v[1]), pk2h(v[2], v[3]));
            }
        }
    } else if (t == 1) {
#pragma unroll
        for (int i = 0; i < 4; ++i) {
            const int Rb = r0 + wi * 64 + i * 16 + kg * 4;
            const int h  = (Rb >> 6) & 15;
            const int e0 = Rb & 63;
            const int ksf = e0 >> 4, Hf = (e0 >> 3) & 1, j0 = e0 & 7;
            float bv4[4];
#pragma unroll
            for (int r = 0; r < 4; ++r) bv4[r] = bk[(Rb & 1023) + r];
#pragma unroll
            for (int j = 0; j < 4; ++j) {
                const int s  = c0 + wj * 64 + j * 16 + ml;
                const int bb = s >> 11, sl = s & (S - 1);
                const int bh = bb * H + h;
                const int kt = sl >> 6, sub = (sl >> 5) & 1, klow = sl & 31;
                const int lanef = klow | (Hf << 5);
                const size_t off = (size_t)bh * 131072 +
                    (size_t)(((kt * 2 + sub) * 4 + ksf) * 64 + lanef) * 8 + j0;
                float v[4];
#pragma unroll
                for (int r = 0; r < 4; ++r) v[r] = (acc[i][j][r] + bv4[r]) * KSC;
                *(uint2*)&khF[off] = make_uint2(pk2h(v[0], v[1]), pk2h(v[2], v[3]));
            }
        }
    } else {
#pragma unroll
        for (int i = 0; i < 4; ++i) {
            const int Rb  = r0 + wi * 64 + i * 16 + kg * 4;
            const int h   = (Rb >> 6) & 15;
            const int dh0 = Rb & 63;
            float bv4[4];
#pragma unroll
            for (int r = 0; r < 4; ++r) bv4[r] = bv[(Rb & 1023) + r];
#pragma unroll
            for (int j = 0; j < 4; ++j) {
                const int s  = c0 + wj * 64 + j * 16 + ml;
                const int bb = s >> 11, sl = s & (S - 1);
                const int bh = bb * H + h;
                const int kt = sl >> 6, key = sl & 63;
                const int ksf = key >> 4, Hf = (key >> 3) & 1, j0 = key & 7;
                const size_t tb = (size_t)bh * 131072 + (size_t)j0 +
                                  (size_t)((kt * 2) * 4 + ksf) * 512;
#pragma unroll
                for (int r = 0; r < 4; ++r) {
                    const int dh = dh0 + r;
                    const int sub = dh >> 5;
                    const int lanef = (dh & 31) | (Hf << 5);
                    vhF[tb + (size_t)sub * 2048 + (size_t)lanef * 8] =
                        f2h(acc[i][j][r] + bv4[r]);
                }
            }
        }
    }
}

// ---------------------------------------------------------------------------
// attention: R13 structure, fp16 dtype (proven 84.6us). 1D grid 512, 512 thr
// (2 key-groups x 4 waves). Decode: bh = (id&7) | (((id>>3)&3)<<3), qt = id>>5
// -> all 16 qt-blocks of a bh share id%8 (same XCD; K/V L2-resident).
// Double-buffered glds16 prefetch, ONE barrier/iter. No-max exp2 softmax
// (raw v_exp_f32, l deferred); shfl P-exchange (proven). ctx single fp16.
// Regs: 64 arch + 64 acc = 128 = 4 waves/SIMD tier; LDS 66.5KB = 2 blocks/CU.
// ---------------------------------------------------------------------------
__global__ __launch_bounds__(512, 4) void attention_mfma(
    const u16* __restrict__ qh, const u16* __restrict__ khF,
    const u16* __restrict__ vhF, u16* __restrict__ cth)
{
    const int id  = blockIdx.x;
    const int bh  = (id & 7) | (((id >> 3) & 3) << 3);   // 0..31
    const int qt  = id >> 5;                              // 0..15
    const int b   = bh >> 4, h = bh & 15;
    const int tid = threadIdx.x;
    const int w   = tid >> 6, wl = w & 3, g = w >> 2;
    const int lane = tid & 63;
    const int nq  = lane & 31;
    const int Hh  = lane >> 5;

    __shared__ union {
        u16   stg[2][2][2][4096];   // [group][buf][K,V][64keys x 64dh] = 64KB
        float xch[128][72];         // merge/output buffer 36.9KB
    } L;
    __shared__ float lsum[2][128];

    // Q fragments (B-operand), register resident: dh = ks*16 + Hh*8 + j
    const int qrow = qt * 128 + wl * 32 + nq;
    const u16* qhp = qh + ((size_t)bh * S + qrow) * DH;
    frag8h qf[4];
#pragma unroll
    for (int ks = 0; ks < 4; ++ks) qf[ks] = *(const frag8h*)(qhp + ks * 16 + Hh * 8);

    f32x16 O0, O1;
#pragma unroll
    for (int i = 0; i < 16; ++i) { O0[i] = 0.f; O1[i] = 0.f; }
    float l_run = 0.f;

    const int go = wl * 1024 + lane * 8;
    const size_t bhb = (size_t)bh * 131072;

    // prefetch tile 0 into buf 0
    {
        const size_t kb = bhb + (size_t)(g * 16) * 4096;
        glds16(khF + kb + go,       &L.stg[g][0][0][wl * 1024]);
        glds16(khF + kb + go + 512, &L.stg[g][0][0][wl * 1024 + 512]);
        glds16(vhF + kb + go,       &L.stg[g][0][1][wl * 1024]);
        glds16(vhF + kb + go + 512, &L.stg[g][0][1][wl * 1024 + 512]);
    }

    for (int it = 0; it < 16; ++it) {
        __syncthreads();   // buf[it&1] loads drained; prev reads of buf[(it+1)&1] done
        if (it < 15) {     // prefetch next tile into the other buffer
            const size_t kb = bhb + (size_t)(g * 16 + it + 1) * 4096;
            const int nb = (it + 1) & 1;
            glds16(khF + kb + go,       &L.stg[g][nb][0][wl * 1024]);
            glds16(khF + kb + go + 512, &L.stg[g][nb][0][wl * 1024 + 512]);
            glds16(vhF + kb + go,       &L.stg[g][nb][1][wl * 1024]);
            glds16(vhF + kb + go + 512, &L.stg[g][nb][1][wl * 1024 + 512]);
        }
        const u16* sK = &L.stg[g][it & 1][0][0];
        const u16* sV = &L.stg[g][it & 1][1][0];

        // ---- S^T = K·Q^T  (K scaled by KSC at build time)
        f32x16 sa0, sa1;
#pragma unroll
        for (int i = 0; i < 16; ++i) { sa0[i] = 0.f; sa1[i] = 0.f; }
#pragma unroll
        for (int ks = 0; ks < 4; ++ks) {
            frag8h k0 = *(const frag8h*)&sK[(ks * 64 + lane) * 8];
            frag8h k1 = *(const frag8h*)&sK[((4 + ks) * 64 + lane) * 8];
            sa0 = __builtin_amdgcn_mfma_f32_32x32x16_f16(k0, qf[ks], sa0, 0, 0, 0);
            sa1 = __builtin_amdgcn_mfma_f32_32x32x16_f16(k1, qf[ks], sa1, 0, 0, 0);
        }

        // ---- no-max softmax numerators; l accumulated per-lane (merge deferred)
        float psum = 0.f;
        u32 ph0[8], ph1[8];
#pragma unroll
        for (int u = 0; u < 8; ++u) {
            float e0 = EXP2(sa0[2 * u]);
            float e1 = EXP2(sa0[2 * u + 1]);
            float f0 = EXP2(sa1[2 * u]);
            float f1 = EXP2(sa1[2 * u + 1]);
            psum += (e0 + e1) + (f0 + f1);
            ph0[u] = pk2h(e0, e1);
            ph1[u] = pk2h(f0, f1);
        }
        l_run += psum;

        // ---- O^T += V^T · P^T  (P^T B-frags via half-swap shuffles)
#pragma unroll
        for (int ks = 0; ks < 4; ++ks) {
            const u32* PH = (ks < 2) ? ph0 : ph1;
            const int ks2 = ks & 1;
            const int oi = 4 * ks2 + 2 * Hh;
            const int si = 4 * ks2 + 2 * (1 - Hh);
            u32 rh0 = __shfl_xor(PH[si], 32), rh1 = __shfl_xor(PH[si + 1], 32);
            union { u32 u[4]; frag8h f; } fh;
            if (Hh == 0) {
                fh.u[0] = PH[oi]; fh.u[1] = PH[oi + 1]; fh.u[2] = rh0; fh.u[3] = rh1;
            } else {
                fh.u[0] = rh0; fh.u[1] = rh1; fh.u[2] = PH[oi]; fh.u[3] = PH[oi + 1];
            }
            frag8h v0 = *(const frag8h*)&sV[(ks * 64 + lane) * 8];
            frag8h v1 = *(const frag8h*)&sV[((4 + ks) * 64 + lane) * 8];
            O0 = __builtin_amdgcn_mfma_f32_32x32x16_f16(v0, fh.f, O0, 0, 0, 0);
            O1 = __builtin_amdgcn_mfma_f32_32x32x16_f16(v1, fh.f, O1, 0, 0, 0);
        }
    }

    // ---- merge the two key-groups (plain sums; no m)
    l_run += __shfl_xor(l_run, 32);
    const int qr = wl * 32 + nq;
    if (Hh == 0) lsum[g][qr] = l_run;
    __syncthreads();                   // all stg reads done; union reuse safe
    const float invl = 1.f / (lsum[0][qr] + lsum[1][qr]);

    if (g == 1) {
#pragma unroll
        for (int cdh = 0; cdh < 2; ++cdh)
#pragma unroll
            for (int rg = 0; rg < 4; ++rg) {
                const f32x16& O = cdh ? O1 : O0;
                float4 v4;
                v4.x = O[4 * rg + 0]; v4.y = O[4 * rg + 1];
                v4.z = O[4 * rg + 2]; v4.w = O[4 * rg + 3];
                *(float4*)&L.xch[qr][cdh * 32 + rg * 8 + Hh * 4] = v4;
            }
    }
    __syncthreads();
    if (g == 0) {
#pragma unroll
        for (int cdh = 0; cdh < 2; ++cdh)
#pragma unroll
            for (int rg = 0; rg < 4; ++rg) {
                float4 p4 = *(const float4*)&L.xch[qr][cdh * 32 + rg * 8 + Hh * 4];
                const f32x16& O = cdh ? O1 : O0;
                float4 v4;
                v4.x = (O[4 * rg + 0] + p4.x) * invl;
                v4.y = (O[4 * rg + 1] + p4.y) * invl;
                v4.z = (O[4 * rg + 2] + p4.z) * invl;
                v4.w = (O[4 * rg + 3] + p4.w) * invl;
                *(float4*)&L.xch[qr][cdh * 32 + rg * 8 + Hh * 4] = v4;
            }
    }
    __syncthreads();
#pragma unroll
    for (int pass = 0; pass < 4; ++pass) {
        const int chunk = pass * 512 + tid;          // 0..2047
        const int qi = chunk >> 4, seg = chunk & 15;
        float4 v4 = *(const float4*)&L.xch[qi][seg * 4];
        const size_t base = ((size_t)(b * S + qt * 128 + qi)) * D + h * DH + seg * 4;
        *(uint2*)&cth[base] = make_uint2(pk2h(v4.x, v4.y), pk2h(v4.z, v4.w));
    }
}

// ---------------------------------------------------------------------------
// gemm_out: out[s][d] = sum_k ctx[s,k]*Wo[k,d] + bo. fp16 single-pass.
// 128x128 tile (was 128x64): clone of gemm_qkv K-loop. grid (32,8).
// Kept at (256,3) to isolate gemm_qkv's occupancy experiment.
// ---------------------------------------------------------------------------
__global__ __launch_bounds__(256, 3) void gemm_out(
    const u16* __restrict__ Ah, const u16* __restrict__ Bh,
    const float* __restrict__ bo, float* __restrict__ out)
{
    const int r0  = blockIdx.x * 128;     // s
    const int c0  = blockIdx.y * 128;     // d
    const int tid = threadIdx.x;
    const int w = tid >> 6, lane = tid & 63;
    const int wi = w >> 1, wj = w & 1;
    const int ml = lane & 15, kg = lane >> 4;

    __shared__ u16 Ta[2][128 * 32];
    __shared__ u16 Tb[2][128 * 32];

    const int srow = lane >> 2, sseg = lane & 3;
    const u16* Ag = Ah + (size_t)(r0 + w * 32 + srow) * 1024 + sseg * 8;
    const u16* Bg = Bh + (size_t)(c0 + w * 32 + srow) * 1024 + sseg * 8;

    f32x4 acc[4][4];
#pragma unroll
    for (int i = 0; i < 4; ++i)
#pragma unroll
        for (int j = 0; j < 4; ++j)
#pragma unroll
            for (int r = 0; r < 4; ++r) acc[i][j][r] = 0.f;

    for (int k0 = 0; k0 < 1024; k0 += 64) {
        __syncthreads();
#pragma unroll
        for (int hb = 0; hb < 2; ++hb) {
            const int ko = k0 + hb * 32;
            glds16(Ag + ko,             &Ta[hb][(w * 32) * 32]);
            glds16(Ag + 16 * 1024 + ko, &Ta[hb][(w * 32 + 16) * 32]);
            glds16(Bg + ko,             &Tb[hb][(w * 32) * 32]);
            glds16(Bg + 16 * 1024 + ko, &Tb[hb][(w * 32 + 16) * 32]);
        }
        __syncthreads();

#pragma unroll
        for (int hb = 0; hb < 2; ++hb) {
            frag8h af[4], bf[4];
#pragma unroll
            for (int i = 0; i < 4; ++i)
                af[i] = *(const frag8h*)&Ta[hb][(wi * 64 + i * 16 + ml) * 32 + kg * 8];
#pragma unroll
            for (int j = 0; j < 4; ++j)
                bf[j] = *(const frag8h*)&Tb[hb][(wj * 64 + j * 16 + ml) * 32 + kg * 8];
#pragma unroll
            for (int i = 0; i < 4; ++i)
#pragma unroll
                for (int j = 0; j < 4; ++j)
                    acc[i][j] = __builtin_amdgcn_mfma_f32_16x16x32_f16(af[i], bf[j], acc[i][j], 0, 0, 0);
        }
    }

    // epilogue: rows = s (A), cols(ml) = d (B); coalesced fp32 stores
#pragma unroll
    for (int i = 0; i < 4; ++i) {
        const int R0 = r0 + wi * 64 + i * 16 + kg * 4;
#pragma unroll
        for (int j = 0; j < 4; ++j) {
            const int col = c0 + wj * 64 + j * 16 + ml;
            const float bval = bo[col];
#pragma unroll
            for (int r = 0; r < 4; ++r)
                out[(size_t)(R0 + r) * 1024 + col] = acc[i][j][r] + bval;
        }
    }
}

// ---------------------------------------------------------------------------
extern "C" void kernel_launch(void* const* d_in, const int* in_sizes, int n_in,
                              void* d_out, int out_size, void* d_ws, size_t ws_size,
                              hipStream_t stream) {
    (void)in_sizes; (void)n_in; (void)out_size; (void)ws_size;
    const float* x  = (const float*)d_in[0];
    const float* Wq = (const float*)d_in[1];
    const float* bq = (const float*)d_in[2];
    const float* Wk = (const float*)d_in[3];
    const float* bk = (const float*)d_in[4];
    const float* Wv = (const float*)d_in[5];
    const float* bv = (const float*)d_in[6];
    const float* Wo = (const float*)d_in[7];
    const float* bo = (const float*)d_in[8];
    float* out = (float*)d_out;

    // Workspace: 5 x NPER u16 = 41.9 MB.
    //   xh dead after gemm_qkv -> cth (attention output overlay)
    const size_t NPER = (size_t)BS * D;              // 4,194,304
    u16* base = (u16*)d_ws;
    u16* xh  = base;
    u16* Wt  = base + NPER;
    u16* qh  = base + 2 * NPER;
    u16* khF = base + 3 * NPER;
    u16* vhF = base + 4 * NPER;
    u16* cth = xh;                                   // overlays xh

    convert_x  <<<dim3(BS * D / 1024), 256, 0, stream>>>(x, xh);
    transpose_w<<<dim3(16, 64),        256, 0, stream>>>(Wq, Wk, Wv, Wo, Wt);
    gemm_qkv   <<<dim3(32, 24), 256, 0, stream>>>(Wt, xh, bq, bk, bv,
                                                  qh, khF, vhF);
    attention_mfma<<<dim3(512), 512, 0, stream>>>(qh, khF, vhF, cth);
    gemm_out   <<<dim3(32, 8), 256, 0, stream>>>(cth, Wt + (size_t)3072 * 1024,
                                                 bo, out);
}

// Round 12
// 215.827 us; speedup vs baseline: 1.0380x; 1.0380x over previous
//
#include <hip/hip_runtime.h>
#include <hip/hip_fp16.h>

// DPMultiHeadAttention MI355X — Round 21 = R19 restored (best measured:
// 209.7us total, absmax 1.95e-3).
// R20 post-mortem: both GEMM edits regressed (+14us) for GRID reasons the
// reg-model missed: gemm_out 128x128 -> grid 256 = 1 block/CU = 1 wave/SIMD
// (TLP destroyed); gemm_qkv (256,4) -> grid 768 = 3 blocks/CU max anyway, so
// the tighter reg cap bought nothing. Occupancy = min(grid/CU, LDS, regs) —
// check ALL three. R19 config: gemm_qkv (256,3) grid (32,24); gemm_out
// 128x64 (256,4) grid (32,16).
// Pipeline (validated R19): fp16 single-pass everywhere; attention = R13
// structure (dual wall: 128 regs/thread + 64KB LDS, R15/R16 proved both),
// raw v_exp_f32 softmax, shfl P-exchange, XCD-swizzled block decode.

constexpr int B  = 2;
constexpr int S  = 2048;
constexpr int D  = 1024;
constexpr int H  = 16;
constexpr int DH = 64;
constexpr int BS = B * S;   // 4096

using u16 = unsigned short;
using u32 = unsigned int;
using frag8h = __attribute__((ext_vector_type(8)))  _Float16;
using f32x4  = __attribute__((ext_vector_type(4)))  float;
using f32x16 = __attribute__((ext_vector_type(16))) float;

__device__ inline u16 f2h(float x) {
    __half t = __float2half_rn(x);
    union { __half h; u16 u; } c; c.h = t; return c.u;
}
__device__ inline u32 pk2h(float a, float b) {
    __half2 t = __float22half2_rn(make_float2(a, b));
    union { __half2 h; u32 u; } c; c.h = t; return c.u;
}

#if __has_builtin(__builtin_amdgcn_exp2f)
#define EXP2(x) __builtin_amdgcn_exp2f(x)
#else
#define EXP2(x) exp2f(x)
#endif

__device__ inline void glds16(const u16* g, const u16* l) {
    __builtin_amdgcn_global_load_lds(
        (const __attribute__((address_space(1))) void*)g,
        (__attribute__((address_space(3))) void*)l, 16, 0, 0);
}

// score scale: 1/sqrt(DH) * log2(e) (exp2-domain softmax), folded into K
#define KSC (0.125f * 1.44269504088896f)

// ---------------------------------------------------------------------------
// convert_x: x fp32 [4096][1024] -> xh fp16 (single array; no split)
// ---------------------------------------------------------------------------
__global__ __launch_bounds__(256) void convert_x(
    const float* __restrict__ x, u16* __restrict__ xh)
{
    const size_t idx = ((size_t)blockIdx.x * 256 + threadIdx.x) * 4;
    float4 v = *(const float4*)&x[idx];
    *(uint2*)&xh[idx] = make_uint2(pk2h(v.x, v.y), pk2h(v.z, v.w));
}

// ---------------------------------------------------------------------------
// transpose_w: Wt[4096][1024] fp16, k-contiguous rows.
// rows [0,3072): Wt[(t*16+h)*64+e][k] = W_t[h][k][e]; rows [3072,4096): Wo^T.
// ---------------------------------------------------------------------------
__global__ __launch_bounds__(256) void transpose_w(
    const float* __restrict__ Wq, const float* __restrict__ Wk,
    const float* __restrict__ Wv, const float* __restrict__ Wo,
    u16* __restrict__ Wt)
{
    const int kt = blockIdx.x;      // 0..15
    const int sl = blockIdx.y;      // 0..63
    const int tid = threadIdx.x;
    __shared__ float Ls[64][68];

    const float* src; int rstride;
    if (sl < 48) {
        const int t = sl >> 4, h = sl & 15;
        const float* Wp = (t == 0) ? Wq : ((t == 1) ? Wk : Wv);
        src = Wp + (size_t)h * D * DH;
        rstride = 64;
    } else {
        src = Wo + (sl - 48) * 64;
        rstride = 1024;
    }

    const int rr = tid >> 4, c4 = tid & 15;
#pragma unroll
    for (int p = 0; p < 4; ++p) {
        const int kk = p * 16 + rr;
        float4 v = *(const float4*)&src[(size_t)(kt * 64 + kk) * rstride + c4 * 4];
        *(float4*)&Ls[kk][c4 * 4] = v;
    }
    __syncthreads();
    const int rl = tid >> 2, ks = tid & 3;
    u16 ob[16];
#pragma unroll
    for (int i = 0; i < 16; ++i) ob[i] = f2h(Ls[ks * 16 + i][rl]);
    u16* dst = Wt + (size_t)(sl * 64 + rl) * 1024 + kt * 64 + ks * 16;
    *(uint4*)&dst[0] = *(uint4*)&ob[0];
    *(uint4*)&dst[8] = *(uint4*)&ob[8];
}

// ---------------------------------------------------------------------------
// gemm_qkv: C[n][s] = sum_k Wt[n,k]*x[s,k]. fp16 single-pass.
// 128x128 tile, 32 MFMA per barrier pair. grid (32,24): x=s-tile, y=n-tile.
// (256,3): grid caps at 3 blocks/CU anyway (768/256) — do not tighten regs.
// Epilogue: q -> qh row-major [bh][s][64]; k -> khF (scaled KSC); v -> vhF.
// Fragment granule per (bh,kt): off = ((sub*4+ks)*64+lane)*8+j
// ---------------------------------------------------------------------------
__global__ __launch_bounds__(256, 3) void gemm_qkv(
    const u16* __restrict__ Wt, const u16* __restrict__ xh,
    const float* __restrict__ bq, const float* __restrict__ bk, const float* __restrict__ bv,
    u16* __restrict__ qhO, u16* __restrict__ khF, u16* __restrict__ vhF)
{
    const int r0  = blockIdx.y * 128;     // n
    const int c0  = blockIdx.x * 128;     // s
    const int tid = threadIdx.x;
    const int w = tid >> 6, lane = tid & 63;
    const int wi = w >> 1, wj = w & 1;
    const int ml = lane & 15, kg = lane >> 4;

    __shared__ u16 Ta[2][128 * 32];
    __shared__ u16 Tb[2][128 * 32];

    const int srow = lane >> 2, sseg = lane & 3;
    const u16* Ag = Wt + (size_t)(r0 + w * 32 + srow) * 1024 + sseg * 8;
    const u16* Bg = xh + (size_t)(c0 + w * 32 + srow) * 1024 + sseg * 8;

    f32x4 acc[4][4];
#pragma unroll
    for (int i = 0; i < 4; ++i)
#pragma unroll
        for (int j = 0; j < 4; ++j)
#pragma unroll
            for (int r = 0; r < 4; ++r) acc[i][j][r] = 0.f;

    for (int k0 = 0; k0 < 1024; k0 += 64) {
        __syncthreads();
#pragma unroll
        for (int hb = 0; hb < 2; ++hb) {
            const int ko = k0 + hb * 32;
            glds16(Ag + ko,             &Ta[hb][(w * 32) * 32]);
            glds16(Ag + 16 * 1024 + ko, &Ta[hb][(w * 32 + 16) * 32]);
            glds16(Bg + ko,             &Tb[hb][(w * 32) * 32]);
            glds16(Bg + 16 * 1024 + ko, &Tb[hb][(w * 32 + 16) * 32]);
        }
        __syncthreads();

#pragma unroll
        for (int hb = 0; hb < 2; ++hb) {
            frag8h af[4], bf[4];
#pragma unroll
            for (int i = 0; i < 4; ++i)
                af[i] = *(const frag8h*)&Ta[hb][(wi * 64 + i * 16 + ml) * 32 + kg * 8];
#pragma unroll
            for (int j = 0; j < 4; ++j)
                bf[j] = *(const frag8h*)&Tb[hb][(wj * 64 + j * 16 + ml) * 32 + kg * 8];
#pragma unroll
            for (int i = 0; i < 4; ++i)
#pragma unroll
                for (int j = 0; j < 4; ++j)
                    acc[i][j] = __builtin_amdgcn_mfma_f32_16x16x32_f16(af[i], bf[j], acc[i][j], 0, 0, 0);
        }
    }

    // epilogue: C/D col = ml (s), rows = n
    const int t = r0 >> 10;                      // 0:q 1:k 2:v
    if (t == 0) {
#pragma unroll
        for (int i = 0; i < 4; ++i) {
            const int Rb = r0 + wi * 64 + i * 16 + kg * 4;
            const int h  = (Rb >> 6) & 15;
            const int e0 = Rb & 63;
            float bv4[4];
#pragma unroll
            for (int r = 0; r < 4; ++r) bv4[r] = bq[(Rb & 1023) + r];
#pragma unroll
            for (int j = 0; j < 4; ++j) {
                const int s  = c0 + wj * 64 + j * 16 + ml;
                const int bb = s >> 11, sl = s & (S - 1);
                float v[4];
#pragma unroll
                for (int r = 0; r < 4; ++r) v[r] = acc[i][j][r] + bv4[r];
                const size_t base = ((size_t)(bb * H + h) * S + sl) * 64 + e0;
                *(uint2*)&qhO[base] = make_uint2(pk2h(v[0], v[1]), pk2h(v[2], v[3]));
            }
        }
    } else if (t == 1) {
#pragma unroll
        for (int i = 0; i < 4; ++i) {
            const int Rb = r0 + wi * 64 + i * 16 + kg * 4;
            const int h  = (Rb >> 6) & 15;
            const int e0 = Rb & 63;
            const int ksf = e0 >> 4, Hf = (e0 >> 3) & 1, j0 = e0 & 7;
            float bv4[4];
#pragma unroll
            for (int r = 0; r < 4; ++r) bv4[r] = bk[(Rb & 1023) + r];
#pragma unroll
            for (int j = 0; j < 4; ++j) {
                const int s  = c0 + wj * 64 + j * 16 + ml;
                const int bb = s >> 11, sl = s & (S - 1);
                const int bh = bb * H + h;
                const int kt = sl >> 6, sub = (sl >> 5) & 1, klow = sl & 31;
                const int lanef = klow | (Hf << 5);
                const size_t off = (size_t)bh * 131072 +
                    (size_t)(((kt * 2 + sub) * 4 + ksf) * 64 + lanef) * 8 + j0;
                float v[4];
#pragma unroll
                for (int r = 0; r < 4; ++r) v[r] = (acc[i][j][r] + bv4[r]) * KSC;
                *(uint2*)&khF[off] = make_uint2(pk2h(v[0], v[1]), pk2h(v[2], v[3]));
            }
        }
    } else {
#pragma unroll
        for (int i = 0; i < 4; ++i) {
            const int Rb  = r0 + wi * 64 + i * 16 + kg * 4;
            const int h   = (Rb >> 6) & 15;
            const int dh0 = Rb & 63;
            float bv4[4];
#pragma unroll
            for (int r = 0; r < 4; ++r) bv4[r] = bv[(Rb & 1023) + r];
#pragma unroll
            for (int j = 0; j < 4; ++j) {
                const int s  = c0 + wj * 64 + j * 16 + ml;
                const int bb = s >> 11, sl = s & (S - 1);
                const int bh = bb * H + h;
                const int kt = sl >> 6, key = sl & 63;
                const int ksf = key >> 4, Hf = (key >> 3) & 1, j0 = key & 7;
                const size_t tb = (size_t)bh * 131072 + (size_t)j0 +
                                  (size_t)((kt * 2) * 4 + ksf) * 512;
#pragma unroll
                for (int r = 0; r < 4; ++r) {
                    const int dh = dh0 + r;
                    const int sub = dh >> 5;
                    const int lanef = (dh & 31) | (Hf << 5);
                    vhF[tb + (size_t)sub * 2048 + (size_t)lanef * 8] =
                        f2h(acc[i][j][r] + bv4[r]);
                }
            }
        }
    }
}

// ---------------------------------------------------------------------------
// attention: R13 structure, fp16 dtype (proven 82-85us). 1D grid 512, 512 thr
// (2 key-groups x 4 waves). Decode: bh = (id&7) | (((id>>3)&3)<<3), qt = id>>5
// -> all 16 qt-blocks of a bh share id%8 (same XCD; K/V L2-resident).
// Double-buffered glds16 prefetch, ONE barrier/iter. No-max exp2 softmax
// (raw v_exp_f32, l deferred); shfl P-exchange (proven). ctx single fp16.
// Regs: 64 arch + 64 acc = 128 = 4 waves/SIMD tier; LDS 66.5KB = 2 blocks/CU.
// Both resource walls verified (R15 regs, R16 LDS) — do not perturb.
// ---------------------------------------------------------------------------
__global__ __launch_bounds__(512, 4) void attention_mfma(
    const u16* __restrict__ qh, const u16* __restrict__ khF,
    const u16* __restrict__ vhF, u16* __restrict__ cth)
{
    const int id  = blockIdx.x;
    const int bh  = (id & 7) | (((id >> 3) & 3) << 3);   // 0..31
    const int qt  = id >> 5;                              // 0..15
    const int b   = bh >> 4, h = bh & 15;
    const int tid = threadIdx.x;
    const int w   = tid >> 6, wl = w & 3, g = w >> 2;
    const int lane = tid & 63;
    const int nq  = lane & 31;
    const int Hh  = lane >> 5;

    __shared__ union {
        u16   stg[2][2][2][4096];   // [group][buf][K,V][64keys x 64dh] = 64KB
        float xch[128][72];         // merge/output buffer 36.9KB
    } L;
    __shared__ float lsum[2][128];

    // Q fragments (B-operand), register resident: dh = ks*16 + Hh*8 + j
    const int qrow = qt * 128 + wl * 32 + nq;
    const u16* qhp = qh + ((size_t)bh * S + qrow) * DH;
    frag8h qf[4];
#pragma unroll
    for (int ks = 0; ks < 4; ++ks) qf[ks] = *(const frag8h*)(qhp + ks * 16 + Hh * 8);

    f32x16 O0, O1;
#pragma unroll
    for (int i = 0; i < 16; ++i) { O0[i] = 0.f; O1[i] = 0.f; }
    float l_run = 0.f;

    const int go = wl * 1024 + lane * 8;
    const size_t bhb = (size_t)bh * 131072;

    // prefetch tile 0 into buf 0
    {
        const size_t kb = bhb + (size_t)(g * 16) * 4096;
        glds16(khF + kb + go,       &L.stg[g][0][0][wl * 1024]);
        glds16(khF + kb + go + 512, &L.stg[g][0][0][wl * 1024 + 512]);
        glds16(vhF + kb + go,       &L.stg[g][0][1][wl * 1024]);
        glds16(vhF + kb + go + 512, &L.stg[g][0][1][wl * 1024 + 512]);
    }

    for (int it = 0; it < 16; ++it) {
        __syncthreads();   // buf[it&1] loads drained; prev reads of buf[(it+1)&1] done
        if (it < 15) {     // prefetch next tile into the other buffer
            const size_t kb = bhb + (size_t)(g * 16 + it + 1) * 4096;
            const int nb = (it + 1) & 1;
            glds16(khF + kb + go,       &L.stg[g][nb][0][wl * 1024]);
            glds16(khF + kb + go + 512, &L.stg[g][nb][0][wl * 1024 + 512]);
            glds16(vhF + kb + go,       &L.stg[g][nb][1][wl * 1024]);
            glds16(vhF + kb + go + 512, &L.stg[g][nb][1][wl * 1024 + 512]);
        }
        const u16* sK = &L.stg[g][it & 1][0][0];
        const u16* sV = &L.stg[g][it & 1][1][0];

        // ---- S^T = K·Q^T  (K scaled by KSC at build time)
        f32x16 sa0, sa1;
#pragma unroll
        for (int i = 0; i < 16; ++i) { sa0[i] = 0.f; sa1[i] = 0.f; }
#pragma unroll
        for (int ks = 0; ks < 4; ++ks) {
            frag8h k0 = *(const frag8h*)&sK[(ks * 64 + lane) * 8];
            frag8h k1 = *(const frag8h*)&sK[((4 + ks) * 64 + lane) * 8];
            sa0 = __builtin_amdgcn_mfma_f32_32x32x16_f16(k0, qf[ks], sa0, 0, 0, 0);
            sa1 = __builtin_amdgcn_mfma_f32_32x32x16_f16(k1, qf[ks], sa1, 0, 0, 0);
        }

        // ---- no-max softmax numerators; l accumulated per-lane (merge deferred)
        float psum = 0.f;
        u32 ph0[8], ph1[8];
#pragma unroll
        for (int u = 0; u < 8; ++u) {
            float e0 = EXP2(sa0[2 * u]);
            float e1 = EXP2(sa0[2 * u + 1]);
            float f0 = EXP2(sa1[2 * u]);
            float f1 = EXP2(sa1[2 * u + 1]);
            psum += (e0 + e1) + (f0 + f1);
            ph0[u] = pk2h(e0, e1);
            ph1[u] = pk2h(f0, f1);
        }
        l_run += psum;

        // ---- O^T += V^T · P^T  (P^T B-frags via half-swap shuffles)
#pragma unroll
        for (int ks = 0; ks < 4; ++ks) {
            const u32* PH = (ks < 2) ? ph0 : ph1;
            const int ks2 = ks & 1;
            const int oi = 4 * ks2 + 2 * Hh;
            const int si = 4 * ks2 + 2 * (1 - Hh);
            u32 rh0 = __shfl_xor(PH[si], 32), rh1 = __shfl_xor(PH[si + 1], 32);
            union { u32 u[4]; frag8h f; } fh;
            if (Hh == 0) {
                fh.u[0] = PH[oi]; fh.u[1] = PH[oi + 1]; fh.u[2] = rh0; fh.u[3] = rh1;
            } else {
                fh.u[0] = rh0; fh.u[1] = rh1; fh.u[2] = PH[oi]; fh.u[3] = PH[oi + 1];
            }
            frag8h v0 = *(const frag8h*)&sV[(ks * 64 + lane) * 8];
            frag8h v1 = *(const frag8h*)&sV[((4 + ks) * 64 + lane) * 8];
            O0 = __builtin_amdgcn_mfma_f32_32x32x16_f16(v0, fh.f, O0, 0, 0, 0);
            O1 = __builtin_amdgcn_mfma_f32_32x32x16_f16(v1, fh.f, O1, 0, 0, 0);
        }
    }

    // ---- merge the two key-groups (plain sums; no m)
    l_run += __shfl_xor(l_run, 32);
    const int qr = wl * 32 + nq;
    if (Hh == 0) lsum[g][qr] = l_run;
    __syncthreads();                   // all stg reads done; union reuse safe
    const float invl = 1.f / (lsum[0][qr] + lsum[1][qr]);

    if (g == 1) {
#pragma unroll
        for (int cdh = 0; cdh < 2; ++cdh)
#pragma unroll
            for (int rg = 0; rg < 4; ++rg) {
                const f32x16& O = cdh ? O1 : O0;
                float4 v4;
                v4.x = O[4 * rg + 0]; v4.y = O[4 * rg + 1];
                v4.z = O[4 * rg + 2]; v4.w = O[4 * rg + 3];
                *(float4*)&L.xch[qr][cdh * 32 + rg * 8 + Hh * 4] = v4;
            }
    }
    __syncthreads();
    if (g == 0) {
#pragma unroll
        for (int cdh = 0; cdh < 2; ++cdh)
#pragma unroll
            for (int rg = 0; rg < 4; ++rg) {
                float4 p4 = *(const float4*)&L.xch[qr][cdh * 32 + rg * 8 + Hh * 4];
                const f32x16& O = cdh ? O1 : O0;
                float4 v4;
                v4.x = (O[4 * rg + 0] + p4.x) * invl;
                v4.y = (O[4 * rg + 1] + p4.y) * invl;
                v4.z = (O[4 * rg + 2] + p4.z) * invl;
                v4.w = (O[4 * rg + 3] + p4.w) * invl;
                *(float4*)&L.xch[qr][cdh * 32 + rg * 8 + Hh * 4] = v4;
            }
    }
    __syncthreads();
#pragma unroll
    for (int pass = 0; pass < 4; ++pass) {
        const int chunk = pass * 512 + tid;          // 0..2047
        const int qi = chunk >> 4, seg = chunk & 15;
        float4 v4 = *(const float4*)&L.xch[qi][seg * 4];
        const size_t base = ((size_t)(b * S + qt * 128 + qi)) * D + h * DH + seg * 4;
        *(uint2*)&cth[base] = make_uint2(pk2h(v4.x, v4.y), pk2h(v4.z, v4.w));
    }
}

// ---------------------------------------------------------------------------
// gemm_out: out[s][d] = sum_k ctx[s,k]*Wo[k,d] + bo. fp16 single-pass.
// 128x64 tile, grid (32,16) = 512 blocks = 2 blocks/CU (grid-limited;
// the 128x128 variant at 256 blocks = 1 block/CU regressed — R20).
// ---------------------------------------------------------------------------
__global__ __launch_bounds__(256, 4) void gemm_out(
    const u16* __restrict__ Ah, const u16* __restrict__ Bh,
    const float* __restrict__ bo, float* __restrict__ out)
{
    const int r0  = blockIdx.x * 128;     // s
    const int c0  = blockIdx.y * 64;      // d
    const int tid = threadIdx.x;
    const int w = tid >> 6, lane = tid & 63;
    const int ml = lane & 15, kg = lane >> 4;

    __shared__ u16 Ta[2][128 * 32];
    __shared__ u16 Tb[2][64 * 32];

    const int srow = lane >> 2, sseg = lane & 3;
    const u16* Ag = Ah + (size_t)(r0 + w * 32 + srow) * 1024 + sseg * 8;
    const u16* Bg = Bh + (size_t)(c0 + w * 16 + srow) * 1024 + sseg * 8;

    f32x4 acc[2][4];
#pragma unroll
    for (int i = 0; i < 2; ++i)
#pragma unroll
        for (int j = 0; j < 4; ++j)
#pragma unroll
            for (int r = 0; r < 4; ++r) acc[i][j][r] = 0.f;

    for (int k0 = 0; k0 < 1024; k0 += 64) {
        __syncthreads();
#pragma unroll
        for (int hb = 0; hb < 2; ++hb) {
            const int ko = k0 + hb * 32;
            glds16(Ag + ko,             &Ta[hb][(w * 32) * 32]);
            glds16(Ag + 16 * 1024 + ko, &Ta[hb][(w * 32 + 16) * 32]);
            glds16(Bg + ko,             &Tb[hb][(w * 16) * 32]);
        }
        __syncthreads();

#pragma unroll
        for (int hb = 0; hb < 2; ++hb) {
            frag8h af[2], bf[4];
#pragma unroll
            for (int i = 0; i < 2; ++i)
                af[i] = *(const frag8h*)&Ta[hb][(w * 32 + i * 16 + ml) * 32 + kg * 8];
#pragma unroll
            for (int j = 0; j < 4; ++j)
                bf[j] = *(const frag8h*)&Tb[hb][(j * 16 + ml) * 32 + kg * 8];
#pragma unroll
            for (int i = 0; i < 2; ++i)
#pragma unroll
                for (int j = 0; j < 4; ++j)
                    acc[i][j] = __builtin_amdgcn_mfma_f32_16x16x32_f16(af[i], bf[j], acc[i][j], 0, 0, 0);
        }
    }

#pragma unroll
    for (int i = 0; i < 2; ++i) {
        const int R0 = r0 + w * 32 + i * 16 + kg * 4;
#pragma unroll
        for (int j = 0; j < 4; ++j) {
            const int col = c0 + j * 16 + ml;
            const float bval = bo[col];
#pragma unroll
            for (int r = 0; r < 4; ++r)
                out[(size_t)(R0 + r) * 1024 + col] = acc[i][j][r] + bval;
        }
    }
}

// ---------------------------------------------------------------------------
extern "C" void kernel_launch(void* const* d_in, const int* in_sizes, int n_in,
                              void* d_out, int out_size, void* d_ws, size_t ws_size,
                              hipStream_t stream) {
    (void)in_sizes; (void)n_in; (void)out_size; (void)ws_size;
    const float* x  = (const float*)d_in[0];
    const float* Wq = (const float*)d_in[1];
    const float* bq = (const float*)d_in[2];
    const float* Wk = (const float*)d_in[3];
    const float* bk = (const float*)d_in[4];
    const float* Wv = (const float*)d_in[5];
    const float* bv = (const float*)d_in[6];
    const float* Wo = (const float*)d_in[7];
    const float* bo = (const float*)d_in[8];
    float* out = (float*)d_out;

    // Workspace: 5 x NPER u16 = 41.9 MB.
    //   xh dead after gemm_qkv -> cth (attention output overlay)
    const size_t NPER = (size_t)BS * D;              // 4,194,304
    u16* base = (u16*)d_ws;
    u16* xh  = base;
    u16* Wt  = base + NPER;
    u16* qh  = base + 2 * NPER;
    u16* khF = base + 3 * NPER;
    u16* vhF = base + 4 * NPER;
    u16* cth = xh;                                   // overlays xh

    convert_x  <<<dim3(BS * D / 1024), 256, 0, stream>>>(x, xh);
    transpose_w<<<dim3(16, 64),        256, 0, stream>>>(Wq, Wk, Wv, Wo, Wt);
    gemm_qkv   <<<dim3(32, 24), 256, 0, stream>>>(Wt, xh, bq, bk, bv,
                                                  qh, khF, vhF);
    attention_mfma<<<dim3(512), 512, 0, stream>>>(qh, khF, vhF, cth);
    gemm_out   <<<dim3(32, 16), 256, 0, stream>>>(cth, Wt + (size_t)3072 * 1024,
                                                  bo, out);
}